// Round 1
// baseline (547.102 us; speedup 1.0000x reference)
//
#include <hip/hip_runtime.h>
#include <hip/hip_bf16.h>
#include <stdint.h>

typedef _Float16 f16;
typedef __attribute__((ext_vector_type(8))) _Float16 f16x8;
typedef __attribute__((ext_vector_type(4))) float f32x4;

#define M_DIM 2048   // B*S
#define N_DIM 8192   // OUT*32
#define K_DIM 8192   // IN*32
#define BM 128
#define BN 128
#define BK 32

// sign of e_a * e_b = s * e_{a^b} in Cl(4,1), metric diag(+,+,+,+,-) (bit4 = e5)
__device__ __forceinline__ float gp_sign(int a, int b) {
  int sw = 0;
  for (int t = a >> 1; t; t >>= 1) sw += __popc(t & b);
  float s = (sw & 1) ? -1.0f : 1.0f;
  if ((a & b) & 16) s = -s;
  return s;
}

__device__ __forceinline__ void async16(const f16* g, f16* l) {
  __builtin_amdgcn_global_load_lds(
      (const __attribute__((address_space(1))) uint32_t*)g,
      (__attribute__((address_space(3))) uint32_t*)l,
      16, 0, 0);
}

// ---- prep 1: x fp32 -> f16, 8 elems/thread ----
__global__ __launch_bounds__(256) void conv_x_kernel(const float* __restrict__ x,
                                                     f16* __restrict__ Xh) {
  int t = blockIdx.x * 256 + threadIdx.x;
  const float4* xin = (const float4*)x;
  float4 a = xin[2 * t];
  float4 b = xin[2 * t + 1];
  f16x8 h;
  h[0] = (f16)a.x; h[1] = (f16)a.y; h[2] = (f16)a.z; h[3] = (f16)a.w;
  h[4] = (f16)b.x; h[5] = (f16)b.y; h[6] = (f16)b.z; h[7] = (f16)b.w;
  ((f16x8*)Xh)[t] = h;
}

// ---- prep 2: expanded operator  Wh[n*8192 + p] = w[o, i*32 + (k^l)] * s(k^l, l)
// n = o*32+k, p = i*32+l.  XOR-permutation done with shfl_xor (k uniform per block).
__global__ __launch_bounds__(256) void expand_w_kernel(const float* __restrict__ w,
                                                       f16* __restrict__ Wh) {
  int n = blockIdx.x;
  int o = n >> 5, k = n & 31;
  int t = threadIdx.x;
  int l = t & 31;
  int ib = t >> 5;  // 0..7
  float s = gp_sign(k ^ l, l);
  const float* wrow = w + (size_t)o * K_DIM;
  f16* dst = Wh + (size_t)n * K_DIM;
#pragma unroll 4
  for (int c = 0; c < 32; ++c) {
    int i = ib + (c << 3);                 // 0..255
    float v = wrow[(i << 5) + l];          // coalesced, lane l holds w[o,i,l]
    float pv = __shfl_xor(v, k, 32);       // -> w[o,i,l^k]
    dst[(i << 5) + l] = (f16)(pv * s);     // coalesced 2B stores
  }
}

// ---- main GEMM + fused normalize (m97-style 128x128 tile, BK=32) ----
__global__ __launch_bounds__(256) void gemm_vl_kernel(const f16* __restrict__ A,
                                                      const f16* __restrict__ Bw,
                                                      float* __restrict__ C) {
  __shared__ __align__(16) f16 As[BM * BK];  // 8 KB
  __shared__ __align__(16) f16 Bs[BN * BK];  // 8 KB
  const int t = threadIdx.x;
  const int wave = t >> 6, lane = t & 63;
  const int wr = wave >> 1, wc = wave & 1;   // 2x2 wave grid, 64x64 each
  const int g = lane >> 4, lc = lane & 15;
  const int m0 = blockIdx.y * BM, n0 = blockIdx.x * BN;

  f32x4 acc[4][4];
#pragma unroll
  for (int i = 0; i < 4; ++i)
#pragma unroll
    for (int j = 0; j < 4; ++j) {
      acc[i][j][0] = 0.f; acc[i][j][1] = 0.f; acc[i][j][2] = 0.f; acc[i][j][3] = 0.f;
    }

  // staging: tile = 512 x 16B chunks; wave w issue q covers chunks q*256+w*64+lane
  const f16* agp[2]; const f16* bgp[2];
  f16* alp[2]; f16* blp[2];
#pragma unroll
  for (int q = 0; q < 2; ++q) {
    int chunk = (q << 8) + (wave << 6) + lane;   // 0..511
    int row = chunk >> 2;                        // 4 chunks (64B) per row
    int ko = (chunk & 3) << 3;                   // half-offset within row
    agp[q] = A  + (size_t)(m0 + row) * K_DIM + ko;
    bgp[q] = Bw + (size_t)(n0 + row) * K_DIM + ko;
    alp[q] = As + (q << 11) + (wave << 9);       // wave-uniform LDS base
    blp[q] = Bs + (q << 11) + (wave << 9);
  }

  // fragment LDS offsets: A[m=lc][k=g*8+j], B[n=lc][k=g*8+j]
  int aoff[4], boff[4];
#pragma unroll
  for (int i = 0; i < 4; ++i) {
    aoff[i] = ((wr << 6) + (i << 4) + lc) * BK + (g << 3);
    boff[i] = ((wc << 6) + (i << 4) + lc) * BK + (g << 3);
  }

  for (int kk = 0; kk < K_DIM; kk += BK) {
    async16(agp[0] + kk, alp[0]);
    async16(agp[1] + kk, alp[1]);
    async16(bgp[0] + kk, blp[0]);
    async16(bgp[1] + kk, blp[1]);
    __syncthreads();  // drains vmcnt -> LDS ready

    f16x8 av[4], bv[4];
#pragma unroll
    for (int i = 0; i < 4; ++i) av[i] = *(const f16x8*)(As + aoff[i]);
#pragma unroll
    for (int i = 0; i < 4; ++i) bv[i] = *(const f16x8*)(Bs + boff[i]);
#pragma unroll
    for (int tm = 0; tm < 4; ++tm)
#pragma unroll
      for (int tn = 0; tn < 4; ++tn)
        acc[tm][tn] = __builtin_amdgcn_mfma_f32_16x16x32_f16(av[tm], bv[tn],
                                                             acc[tm][tn], 0, 0, 0);
    __syncthreads();  // all reads done before next overwrite
  }

  // epilogue: normalize over each 32-col o-group (tn pairs {0,1} and {2,3})
#pragma unroll
  for (int tm = 0; tm < 4; ++tm) {
    int rowb = m0 + (wr << 6) + (tm << 4) + (g << 2);
#pragma unroll
    for (int r = 0; r < 4; ++r) {
      float v0 = acc[tm][0][r], v1 = acc[tm][1][r];
      float v2 = acc[tm][2][r], v3 = acc[tm][3][r];
      float sa = v0 * v0 + v1 * v1;
      float sb = v2 * v2 + v3 * v3;
#pragma unroll
      for (int msk = 1; msk < 16; msk <<= 1) {   // 16-lane row reduction
        sa += __shfl_xor(sa, msk, 16);
        sb += __shfl_xor(sb, msk, 16);
      }
      float ia = rsqrtf(sa + 1e-6f);
      float ib = rsqrtf(sb + 1e-6f);
      size_t base = (size_t)(rowb + r) * N_DIM + n0 + (wc << 6) + lc;
      C[base]      = v0 * ia;
      C[base + 16] = v1 * ia;
      C[base + 32] = v2 * ib;
      C[base + 48] = v3 * ib;
    }
  }
}

// ---- safety-net fallback if ws is too small: straight fp32, correct but slow ----
__global__ __launch_bounds__(256) void naive_vl_kernel(const float* __restrict__ x,
                                                       const float* __restrict__ w,
                                                       float* __restrict__ out) {
  __shared__ float xs[8192];   // one x row (m)
  __shared__ float sg[1024];   // sg[k*32+l] = s(k^l, l)
  int m = blockIdx.x, o0 = blockIdx.y << 3;
  int t = threadIdx.x;
  for (int i = t; i < 1024; i += 256) {
    int kk = i >> 5, ll = i & 31;
    sg[i] = gp_sign(kk ^ ll, ll);
  }
  const float4* xr = (const float4*)(x + (size_t)m * 8192);
  float4* xs4 = (float4*)xs;
  for (int i = t; i < 2048; i += 256) xs4[i] = xr[i];
  __syncthreads();
  int k = t & 31, ol = t >> 5;
  int o = o0 + ol;
  const float* wrow = w + (size_t)o * 8192;
  float acc = 0.f;
  for (int l = 0; l < 32; ++l) {
    float s = sg[(k << 5) + l];
    const float* wp = wrow + (k ^ l);
    const float* xp = xs + l;
    float part = 0.f;
#pragma unroll 8
    for (int i = 0; i < 256; ++i) part += xp[i << 5] * wp[i << 5];
    acc += part * s;
  }
  float ss = acc * acc;
  for (int msk = 1; msk < 32; msk <<= 1) ss += __shfl_xor(ss, msk, 32);
  out[((size_t)m * 256 + o) * 32 + k] = acc * rsqrtf(ss + 1e-6f);
}

extern "C" void kernel_launch(void* const* d_in, const int* in_sizes, int n_in,
                              void* d_out, int out_size, void* d_ws, size_t ws_size,
                              hipStream_t stream) {
  const float* x = (const float*)d_in[0];
  const float* w = (const float*)d_in[1];
  float* out = (float*)d_out;

  size_t xh_elems = (size_t)M_DIM * K_DIM;   // 16.7M
  size_t wh_elems = (size_t)N_DIM * K_DIM;   // 67.1M
  size_t need = (xh_elems + wh_elems) * sizeof(f16);  // ~168 MB

  if (ws_size >= need) {
    f16* Xh = (f16*)d_ws;
    f16* Wh = Xh + xh_elems;
    conv_x_kernel<<<dim3((M_DIM * K_DIM) / (256 * 8)), dim3(256), 0, stream>>>(x, Xh);
    expand_w_kernel<<<dim3(N_DIM), dim3(256), 0, stream>>>(w, Wh);
    gemm_vl_kernel<<<dim3(N_DIM / BN, M_DIM / BM), dim3(256), 0, stream>>>(Xh, Wh, out);
  } else {
    naive_vl_kernel<<<dim3(M_DIM, 32), dim3(256), 0, stream>>>(x, w, out);
  }
}

// Round 2
// 509.781 us; speedup vs baseline: 1.0732x; 1.0732x over previous
//
#include <hip/hip_runtime.h>
#include <hip/hip_bf16.h>
#include <stdint.h>

typedef _Float16 f16;
typedef __attribute__((ext_vector_type(8))) _Float16 f16x8;
typedef __attribute__((ext_vector_type(4))) float f32x4;

#define M_DIM 2048   // B*S
#define N_DIM 8192   // OUT*32
#define K_DIM 8192   // IN*32
#define BM 128
#define BN 128
#define BK 32

// sign of e_a * e_b = s * e_{a^b} in Cl(4,1), metric diag(+,+,+,+,-) (bit4 = e5)
__device__ __forceinline__ float gp_sign(int a, int b) {
  int sw = 0;
  for (int t = a >> 1; t; t >>= 1) sw += __popc(t & b);
  float s = (sw & 1) ? -1.0f : 1.0f;
  if ((a & b) & 16) s = -s;
  return s;
}

__device__ __forceinline__ void async16(const f16* g, f16* l) {
  __builtin_amdgcn_global_load_lds(
      (const __attribute__((address_space(1))) uint32_t*)g,
      (__attribute__((address_space(3))) uint32_t*)l,
      16, 0, 0);
}

// ---- prep 1: x fp32 -> f16, 8 elems/thread ----
__global__ __launch_bounds__(256) void conv_x_kernel(const float* __restrict__ x,
                                                     f16* __restrict__ Xh) {
  int t = blockIdx.x * 256 + threadIdx.x;
  const float4* xin = (const float4*)x;
  float4 a = xin[2 * t];
  float4 b = xin[2 * t + 1];
  f16x8 h;
  h[0] = (f16)a.x; h[1] = (f16)a.y; h[2] = (f16)a.z; h[3] = (f16)a.w;
  h[4] = (f16)b.x; h[5] = (f16)b.y; h[6] = (f16)b.z; h[7] = (f16)b.w;
  ((f16x8*)Xh)[t] = h;
}

// ---- prep 2: expanded operator  Wh[n*8192 + p] = w[o, i*32 + (k^l)] * s(k^l, l)
// n = o*32+k, p = i*32+l.  One block handles (o, 8 k-values); i-tiled through
// LDS (padded +1 to kill read conflicts); f16x8 vector stores.
__global__ __launch_bounds__(256) void expand_w_kernel(const float* __restrict__ w,
                                                       f16* __restrict__ Wh) {
  __shared__ float ws[64 * 33];   // i-tile of 64 rows, padded
  __shared__ float sg[8 * 32];    // sign table for this block's 8 k values
  const int bid = blockIdx.x;
  const int o = bid >> 2, k0 = (bid & 3) << 3;
  const int t = threadIdx.x;
  const float* wrow = w + (size_t)o * K_DIM;

  {
    int kk = k0 + (t >> 5), ll = t & 31;
    sg[t] = gp_sign(kk ^ ll, ll);
  }

  for (int it = 0; it < 4; ++it) {           // 4 i-tiles of 64 rows
    __syncthreads();
    // stage 64x32 floats, padded to stride 33
#pragma unroll
    for (int c = t; c < 512; c += 256) {     // float4 granularity
      float4 v = ((const float4*)(wrow + (it << 11)))[c];
      int i = c >> 3;                        // 0..63
      int j = (c & 7) << 2;
      float* d = ws + i * 33 + j;
      d[0] = v.x; d[1] = v.y; d[2] = v.z; d[3] = v.w;
    }
    __syncthreads();
#pragma unroll
    for (int kq = 0; kq < 8; ++kq) {
      int k = k0 + kq;
      const float* sgr = sg + (kq << 5);
      f16* dst = Wh + ((size_t)(o * 32 + k)) * K_DIM + (it << 11);
      int c = t;                             // one f16x8 chunk per thread
      int i = c >> 2;
      int l0 = (c & 3) << 3;
      f16x8 h;
#pragma unroll
      for (int d = 0; d < 8; ++d) {
        int l = l0 + d;
        h[d] = (f16)(ws[i * 33 + (k ^ l)] * sgr[l]);
      }
      ((f16x8*)dst)[c] = h;
    }
  }
}

// ---- main GEMM + fused normalize (128x128 tile, BK=32, XOR-swizzled LDS) ----
// LDS slot (row, pos) holds global chunk (pos ^ ((row>>1)&3)); fragment reads
// then hit bank = (row&1)<<4 | chunk<<2 | phase  ->  exactly 2-way (free).
__global__ __launch_bounds__(256) void gemm_vl_kernel(const f16* __restrict__ A,
                                                      const f16* __restrict__ Bw,
                                                      float* __restrict__ C) {
  __shared__ __align__(16) f16 As[BM * BK];  // 8 KB
  __shared__ __align__(16) f16 Bs[BN * BK];  // 8 KB
  const int t = threadIdx.x;
  const int wave = t >> 6, lane = t & 63;
  const int wr = wave >> 1, wc = wave & 1;   // 2x2 wave grid, 64x64 each
  const int g = lane >> 4, lc = lane & 15;
  const int m0 = blockIdx.y * BM, n0 = blockIdx.x * BN;

  f32x4 acc[4][4];
#pragma unroll
  for (int i = 0; i < 4; ++i)
#pragma unroll
    for (int j = 0; j < 4; ++j) {
      acc[i][j][0] = 0.f; acc[i][j][1] = 0.f; acc[i][j][2] = 0.f; acc[i][j][3] = 0.f;
    }

  // staging: 512 x 16B chunks; LDS slot c = linear; source chunk XOR-swizzled
  const f16* agp[2]; const f16* bgp[2];
  f16* alp[2]; f16* blp[2];
#pragma unroll
  for (int q = 0; q < 2; ++q) {
    int chunk = (q << 8) + (wave << 6) + lane;       // 0..511 (LDS slot)
    int row = chunk >> 2;
    int gk = ((chunk & 3) ^ ((row >> 1) & 3)) << 3;  // swizzled source chunk
    agp[q] = A  + (size_t)(m0 + row) * K_DIM + gk;
    bgp[q] = Bw + (size_t)(n0 + row) * K_DIM + gk;
    alp[q] = As + (q << 11) + (wave << 9);           // wave-uniform LDS base
    blp[q] = Bs + (q << 11) + (wave << 9);
  }

  // fragment LDS offsets: want global chunk g of row r -> LDS pos g ^ ((r>>1)&3)
  // r = (wr|wc)*64 + i*16 + lc  =>  (r>>1)&3 == (lc>>1)&3 (i,w terms vanish mod 4)
  const int swz = (lc >> 1) & 3;
  int aoff[4], boff[4];
#pragma unroll
  for (int i = 0; i < 4; ++i) {
    aoff[i] = ((wr << 6) + (i << 4) + lc) * BK + ((g ^ swz) << 3);
    boff[i] = ((wc << 6) + (i << 4) + lc) * BK + ((g ^ swz) << 3);
  }

  for (int kk = 0; kk < K_DIM; kk += BK) {
    async16(agp[0] + kk, alp[0]);
    async16(agp[1] + kk, alp[1]);
    async16(bgp[0] + kk, blp[0]);
    async16(bgp[1] + kk, blp[1]);
    __syncthreads();  // drains vmcnt -> LDS ready

    f16x8 av[4], bv[4];
#pragma unroll
    for (int i = 0; i < 4; ++i) av[i] = *(const f16x8*)(As + aoff[i]);
#pragma unroll
    for (int i = 0; i < 4; ++i) bv[i] = *(const f16x8*)(Bs + boff[i]);
#pragma unroll
    for (int tm = 0; tm < 4; ++tm)
#pragma unroll
      for (int tn = 0; tn < 4; ++tn)
        acc[tm][tn] = __builtin_amdgcn_mfma_f32_16x16x32_f16(av[tm], bv[tn],
                                                             acc[tm][tn], 0, 0, 0);
    __syncthreads();  // all reads done before next overwrite
  }

  // epilogue: normalize over each 32-col o-group (tn pairs {0,1} and {2,3})
#pragma unroll
  for (int tm = 0; tm < 4; ++tm) {
    int rowb = m0 + (wr << 6) + (tm << 4) + (g << 2);
#pragma unroll
    for (int r = 0; r < 4; ++r) {
      float v0 = acc[tm][0][r], v1 = acc[tm][1][r];
      float v2 = acc[tm][2][r], v3 = acc[tm][3][r];
      float sa = v0 * v0 + v1 * v1;
      float sb = v2 * v2 + v3 * v3;
#pragma unroll
      for (int msk = 1; msk < 16; msk <<= 1) {   // 16-lane row reduction
        sa += __shfl_xor(sa, msk, 16);
        sb += __shfl_xor(sb, msk, 16);
      }
      float ia = rsqrtf(sa + 1e-6f);
      float ib = rsqrtf(sb + 1e-6f);
      size_t base = (size_t)(rowb + r) * N_DIM + n0 + (wc << 6) + lc;
      C[base]      = v0 * ia;
      C[base + 16] = v1 * ia;
      C[base + 32] = v2 * ib;
      C[base + 48] = v3 * ib;
    }
  }
}

// ---- safety-net fallback if ws is too small: straight fp32, correct but slow ----
__global__ __launch_bounds__(256) void naive_vl_kernel(const float* __restrict__ x,
                                                       const float* __restrict__ w,
                                                       float* __restrict__ out) {
  __shared__ float xs[8192];   // one x row (m)
  __shared__ float sg[1024];   // sg[k*32+l] = s(k^l, l)
  int m = blockIdx.x, o0 = blockIdx.y << 3;
  int t = threadIdx.x;
  for (int i = t; i < 1024; i += 256) {
    int kk = i >> 5, ll = i & 31;
    sg[i] = gp_sign(kk ^ ll, ll);
  }
  const float4* xr = (const float4*)(x + (size_t)m * 8192);
  float4* xs4 = (float4*)xs;
  for (int i = t; i < 2048; i += 256) xs4[i] = xr[i];
  __syncthreads();
  int k = t & 31, ol = t >> 5;
  int o = o0 + ol;
  const float* wrow = w + (size_t)o * 8192;
  float acc = 0.f;
  for (int l = 0; l < 32; ++l) {
    float s = sg[(k << 5) + l];
    const float* wp = wrow + (k ^ l);
    const float* xp = xs + l;
    float part = 0.f;
#pragma unroll 8
    for (int i = 0; i < 256; ++i) part += xp[i << 5] * wp[i << 5];
    acc += part * s;
  }
  float ss = acc * acc;
  for (int msk = 1; msk < 32; msk <<= 1) ss += __shfl_xor(ss, msk, 32);
  out[((size_t)m * 256 + o) * 32 + k] = acc * rsqrtf(ss + 1e-6f);
}

extern "C" void kernel_launch(void* const* d_in, const int* in_sizes, int n_in,
                              void* d_out, int out_size, void* d_ws, size_t ws_size,
                              hipStream_t stream) {
  const float* x = (const float*)d_in[0];
  const float* w = (const float*)d_in[1];
  float* out = (float*)d_out;

  size_t xh_elems = (size_t)M_DIM * K_DIM;   // 16.7M
  size_t wh_elems = (size_t)N_DIM * K_DIM;   // 67.1M
  size_t need = (xh_elems + wh_elems) * sizeof(f16);  // ~168 MB

  if (ws_size >= need) {
    f16* Xh = (f16*)d_ws;
    f16* Wh = Xh + xh_elems;
    conv_x_kernel<<<dim3((M_DIM * K_DIM) / (256 * 8)), dim3(256), 0, stream>>>(x, Xh);
    expand_w_kernel<<<dim3(1024), dim3(256), 0, stream>>>(w, Wh);
    gemm_vl_kernel<<<dim3(N_DIM / BN, M_DIM / BM), dim3(256), 0, stream>>>(Xh, Wh, out);
  } else {
    naive_vl_kernel<<<dim3(M_DIM, 32), dim3(256), 0, stream>>>(x, w, out);
  }
}

// Round 4
// 264.729 us; speedup vs baseline: 2.0666x; 1.9257x over previous
//
#include <hip/hip_runtime.h>
#include <hip/hip_bf16.h>
#include <stdint.h>

typedef _Float16 f16;
typedef __attribute__((ext_vector_type(8))) _Float16 f16x8;
typedef __attribute__((ext_vector_type(4))) float f32x4;

#define M_DIM 2048    // B*S multivector rows
#define K_FULL 8192   // IN*32 (fallback path)
#define M2 8192       // M_DIM*4   (GEMM rows: (m,c))
#define K2 2048       // IN*8      (GEMM K: (i,t,p))
#define N2 2048       // OUT*8     (GEMM cols: (o,r,q))
#define BM 128
#define BN 128
#define BK 32

// ================= compile-time Cl(4,1) -> M(4,C) tables =================
struct CMat { int re[4][4]; int im[4][4]; };

constexpr CMat cmul(const CMat& A, const CMat& B) {
  CMat C{};
  for (int r = 0; r < 4; ++r)
    for (int c = 0; c < 4; ++c) {
      int re = 0, im = 0;
      for (int t = 0; t < 4; ++t) {
        re += A.re[r][t] * B.re[t][c] - A.im[r][t] * B.im[t][c];
        im += A.re[r][t] * B.im[t][c] + A.im[r][t] * B.re[t][c];
      }
      C.re[r][c] = re; C.im[r][c] = im;
    }
  return C;
}

constexpr int gp_sign_ct(int a, int b) {
  int sw = 0;
  for (int t = a >> 1; t; t >>= 1) {
    int x = t & b;
    while (x) { sw += x & 1; x >>= 1; }
  }
  int s = (sw & 1) ? -1 : 1;
  if ((a & b) & 16) s = -s;   // e5^2 = -1
  return s;
}

struct Tables {
  int8_t f_idx[32][4]; int8_t f_sgn[32][4];  // slot -> 4 (blade, sign)
  int8_t g_idx[32][4]; int8_t g_sgn[32][4];  // blade -> 4 (slot, sign)
  bool ok;
};

constexpr Tables make_tables() {
  // gamma matrices: g1..g4 square to +I, g5 to -I, all anticommute
  CMat G[5] = {
    { {{0,0,0,1},{0,0,1,0},{0,1,0,0},{1,0,0,0}},       // s1 x s1
      {{0,0,0,0},{0,0,0,0},{0,0,0,0},{0,0,0,0}} },
    { {{0,0,0,0},{0,0,0,0},{0,0,0,0},{0,0,0,0}},       // s1 x s2
      {{0,0,0,-1},{0,0,1,0},{0,-1,0,0},{1,0,0,0}} },
    { {{0,0,1,0},{0,0,0,-1},{1,0,0,0},{0,-1,0,0}},     // s1 x s3
      {{0,0,0,0},{0,0,0,0},{0,0,0,0},{0,0,0,0}} },
    { {{0,0,0,0},{0,0,0,0},{0,0,0,0},{0,0,0,0}},       // s2 x I
      {{0,0,-1,0},{0,0,0,-1},{1,0,0,0},{0,1,0,0}} },
    { {{0,0,0,0},{0,0,0,0},{0,0,0,0},{0,0,0,0}},       // i * s3 x I
      {{1,0,0,0},{0,1,0,0},{0,0,-1,0},{0,0,0,-1}} } };
  CMat ID{ {{1,0,0,0},{0,1,0,0},{0,0,1,0},{0,0,0,1}},
           {{0,0,0,0},{0,0,0,0},{0,0,0,0},{0,0,0,0}} };
  CMat U[32] = {};
  for (int A = 0; A < 32; ++A) {
    CMat u = ID;
    for (int b = 0; b < 5; ++b) if (A & (1 << b)) u = cmul(u, G[b]);
    U[A] = u;
  }
  bool ok = true;
  // full homomorphism check vs the reference Cayley table convention
  for (int a = 0; a < 32; ++a)
    for (int b = 0; b < 32; ++b) {
      CMat P = cmul(U[a], U[b]);
      int s = gp_sign_ct(a, b);
      const CMat& T = U[a ^ b];
      for (int r = 0; r < 4; ++r)
        for (int c = 0; c < 4; ++c)
          if (P.re[r][c] != s * T.re[r][c] || P.im[r][c] != s * T.im[r][c]) ok = false;
    }
  Tables t{};
  int cnt[32] = {};
  for (int A = 0; A < 32; ++A) {
    int n = 0;
    for (int r = 0; r < 4; ++r)
      for (int c = 0; c < 4; ++c) {
        int vr = U[A].re[r][c], vi = U[A].im[r][c];
        if (vr) {
          int s = (r * 4 + c) * 2;
          if (n < 4 && cnt[s] < 4) {
            t.g_idx[A][n] = (int8_t)s; t.g_sgn[A][n] = (int8_t)vr;
            t.f_idx[s][cnt[s]] = (int8_t)A; t.f_sgn[s][cnt[s]] = (int8_t)vr;
            cnt[s]++;
          } else ok = false;
          n++;
        }
        if (vi) {
          int s = (r * 4 + c) * 2 + 1;
          if (n < 4 && cnt[s] < 4) {
            t.g_idx[A][n] = (int8_t)s; t.g_sgn[A][n] = (int8_t)vi;
            t.f_idx[s][cnt[s]] = (int8_t)A; t.f_sgn[s][cnt[s]] = (int8_t)vi;
            cnt[s]++;
          } else ok = false;
          n++;
        }
      }
    if (n != 4) ok = false;
  }
  for (int s = 0; s < 32; ++s) if (cnt[s] != 4) ok = false;
  t.ok = ok;
  return t;
}

constexpr Tables HT = make_tables();
static_assert(HT.ok, "Cl(4,1) -> M(4,C) homomorphism check FAILED");
__constant__ Tables d_TAB = HT;

// slot numbering: s = (r*4+c)*2 + p, matrix entry (row r, col c), p: 0=re 1=im

__device__ __forceinline__ void async16(const f16* g, f16* l) {
  __builtin_amdgcn_global_load_lds(
      (const __attribute__((address_space(1))) uint32_t*)g,
      (__attribute__((address_space(3))) uint32_t*)l,
      16, 0, 0);
}

__device__ __forceinline__ float gp_sign_rt(int a, int b) {
  int sw = 0;
  for (int t = a >> 1; t; t >>= 1) sw += __popc(t & b);
  float s = (sw & 1) ? -1.0f : 1.0f;
  if ((a & b) & 16) s = -s;
  return s;
}

// ---- forward transform of x: Ag[(m*4+c)*K2 + i*8 + t*2 + p] = part_p X_{m,i}[t][c]
__global__ __launch_bounds__(256) void fwd_x_kernel(const float* __restrict__ x,
                                                    f16* __restrict__ Ag) {
  int tid = blockIdx.x * 256 + threadIdx.x;   // (m,i)
  int m = tid >> 8, i = tid & 255;
  const float4* xp = (const float4*)(x + (size_t)tid * 32);
  float xv[32];
#pragma unroll
  for (int q = 0; q < 8; ++q) {
    float4 v = xp[q];
    xv[q * 4] = v.x; xv[q * 4 + 1] = v.y; xv[q * 4 + 2] = v.z; xv[q * 4 + 3] = v.w;
  }
  float sv[32];
#pragma unroll
  for (int s = 0; s < 32; ++s)
    sv[s] = (float)HT.f_sgn[s][0] * xv[HT.f_idx[s][0]]
          + (float)HT.f_sgn[s][1] * xv[HT.f_idx[s][1]]
          + (float)HT.f_sgn[s][2] * xv[HT.f_idx[s][2]]
          + (float)HT.f_sgn[s][3] * xv[HT.f_idx[s][3]];
#pragma unroll
  for (int c = 0; c < 4; ++c) {
    f16x8 h;
#pragma unroll
    for (int e = 0; e < 8; ++e) {   // e = t*2+p -> slot (t*4+c)*2+p = t*8+c*2+p
      int t = e >> 1, p = e & 1;
      h[e] = (f16)sv[t * 8 + c * 2 + p];
    }
    *(f16x8*)(Ag + ((size_t)(m * 4 + c)) * K2 + i * 8) = h;
  }
}

// ---- forward transform of w: Bt[(o*8+r*2+q)*K2 + i*8 + t*2 + p]
//      q=0: (p==0? ReW[r][t] : -ImW[r][t]);  q=1: (p==0? ImW[r][t] : ReW[r][t])
__global__ __launch_bounds__(256) void fwd_w_kernel(const float* __restrict__ w,
                                                    f16* __restrict__ Bt) {
  int tid = blockIdx.x * 256 + threadIdx.x;   // (o,i)
  int o = tid >> 8, i = tid & 255;
  const float4* wp = (const float4*)(w + (size_t)tid * 32);
  float wv[32];
#pragma unroll
  for (int q = 0; q < 8; ++q) {
    float4 v = wp[q];
    wv[q * 4] = v.x; wv[q * 4 + 1] = v.y; wv[q * 4 + 2] = v.z; wv[q * 4 + 3] = v.w;
  }
  float sv[32];
#pragma unroll
  for (int s = 0; s < 32; ++s)
    sv[s] = (float)HT.f_sgn[s][0] * wv[HT.f_idx[s][0]]
          + (float)HT.f_sgn[s][1] * wv[HT.f_idx[s][1]]
          + (float)HT.f_sgn[s][2] * wv[HT.f_idx[s][2]]
          + (float)HT.f_sgn[s][3] * wv[HT.f_idx[s][3]];
#pragma unroll
  for (int r = 0; r < 4; ++r)
#pragma unroll
    for (int q = 0; q < 2; ++q) {
      f16x8 h;
#pragma unroll
      for (int e = 0; e < 8; ++e) {
        int t = e >> 1, p = e & 1;
        float re = sv[(r * 4 + t) * 2], im = sv[(r * 4 + t) * 2 + 1];
        float v = (q == 0) ? (p == 0 ? re : -im) : (p == 0 ? im : re);
        h[e] = (f16)v;
      }
      *(f16x8*)(Bt + ((size_t)(o * 8 + r * 2 + q)) * K2 + i * 8) = h;
    }
}

// ---- GEMM: P[R][S] = sum_k Ag[R][k]*Bt[S][k];  M2 x K2 x N2, plain f32 out ----
__global__ __launch_bounds__(256) void gemm_mat_kernel(const f16* __restrict__ A,
                                                       const f16* __restrict__ Bw,
                                                       float* __restrict__ P) {
  __shared__ __align__(16) f16 As[BM * BK];
  __shared__ __align__(16) f16 Bs[BN * BK];
  const int t = threadIdx.x;
  const int wave = t >> 6, lane = t & 63;
  const int wr = wave >> 1, wc = wave & 1;
  const int g = lane >> 4, lc = lane & 15;
  const int m0 = blockIdx.y * BM, n0 = blockIdx.x * BN;

  f32x4 acc[4][4];
#pragma unroll
  for (int i = 0; i < 4; ++i)
#pragma unroll
    for (int j = 0; j < 4; ++j) {
      acc[i][j][0] = 0.f; acc[i][j][1] = 0.f; acc[i][j][2] = 0.f; acc[i][j][3] = 0.f;
    }

  const f16* agp[2]; const f16* bgp[2];
  f16* alp[2]; f16* blp[2];
#pragma unroll
  for (int q = 0; q < 2; ++q) {
    int chunk = (q << 8) + (wave << 6) + lane;
    int row = chunk >> 2;
    int gk = ((chunk & 3) ^ ((row >> 1) & 3)) << 3;  // XOR-swizzled source chunk
    agp[q] = A  + (size_t)(m0 + row) * K2 + gk;
    bgp[q] = Bw + (size_t)(n0 + row) * K2 + gk;
    alp[q] = As + (q << 11) + (wave << 9);
    blp[q] = Bs + (q << 11) + (wave << 9);
  }

  const int swz = (lc >> 1) & 3;
  int aoff[4], boff[4];
#pragma unroll
  for (int i = 0; i < 4; ++i) {
    aoff[i] = ((wr << 6) + (i << 4) + lc) * BK + ((g ^ swz) << 3);
    boff[i] = ((wc << 6) + (i << 4) + lc) * BK + ((g ^ swz) << 3);
  }

  for (int kk = 0; kk < K2; kk += BK) {
    async16(agp[0] + kk, alp[0]);
    async16(agp[1] + kk, alp[1]);
    async16(bgp[0] + kk, blp[0]);
    async16(bgp[1] + kk, blp[1]);
    __syncthreads();

    f16x8 av[4], bv[4];
#pragma unroll
    for (int i = 0; i < 4; ++i) av[i] = *(const f16x8*)(As + aoff[i]);
#pragma unroll
    for (int i = 0; i < 4; ++i) bv[i] = *(const f16x8*)(Bs + boff[i]);
#pragma unroll
    for (int tm = 0; tm < 4; ++tm)
#pragma unroll
      for (int tn = 0; tn < 4; ++tn)
        acc[tm][tn] = __builtin_amdgcn_mfma_f32_16x16x32_f16(av[tm], bv[tn],
                                                             acc[tm][tn], 0, 0, 0);
    __syncthreads();
  }

#pragma unroll
  for (int tm = 0; tm < 4; ++tm) {
    int rowb = m0 + (wr << 6) + (tm << 4) + (g << 2);
#pragma unroll
    for (int r = 0; r < 4; ++r) {
      size_t base = (size_t)(rowb + r) * N2 + n0 + (wc << 6) + lc;
      P[base]      = acc[tm][0][r];
      P[base + 16] = acc[tm][1][r];
      P[base + 32] = acc[tm][2][r];
      P[base + 48] = acc[tm][3][r];
    }
  }
}

// ---- inverse transform + normalize:  out[m*8192 + o*32 + k] ----
__global__ __launch_bounds__(256) void inv_norm_kernel(const float* __restrict__ P,
                                                       float* __restrict__ out) {
  __shared__ float ps[4 * N2];   // 32 KB: the 4 GEMM rows of this m
  const int m = blockIdx.x, t = threadIdx.x;
  const float4* src = (const float4*)(P + (size_t)m * 4 * N2);
  float4* dst = (float4*)ps;
#pragma unroll
  for (int c = t; c < N2; c += 256) dst[c] = src[c];   // 4*N2 floats = N2 float4s (BUGFIX: was N2/2)
  __syncthreads();

  const int k = t & 31, og = t >> 5;
  int idx[4]; float sg[4];
#pragma unroll
  for (int j = 0; j < 4; ++j) {
    int s = d_TAB.g_idx[k][j];
    int p = s & 1, cell = s >> 1;
    int r = cell >> 2, c = cell & 3;
    idx[j] = c * N2 + r * 2 + p;
    sg[j] = (float)d_TAB.g_sgn[k][j];
  }
  for (int oi = 0; oi < 32; ++oi) {
    int o = (oi << 3) + og;
    int o8 = o << 3;
    float v = 0.25f * (sg[0] * ps[idx[0] + o8] + sg[1] * ps[idx[1] + o8] +
                       sg[2] * ps[idx[2] + o8] + sg[3] * ps[idx[3] + o8]);
    float ss = v * v;
#pragma unroll
    for (int msk = 1; msk < 32; msk <<= 1) ss += __shfl_xor(ss, msk, 32);
    out[(size_t)m * 8192 + o * 32 + k] = v * rsqrtf(ss + 1e-6f);
  }
}

// ---- safety-net fallback (ws too small): straight fp32 ----
__global__ __launch_bounds__(256) void naive_vl_kernel(const float* __restrict__ x,
                                                       const float* __restrict__ w,
                                                       float* __restrict__ out) {
  __shared__ float xs[8192];
  __shared__ float sgt[1024];
  int m = blockIdx.x, o0 = blockIdx.y << 3;
  int t = threadIdx.x;
  for (int i = t; i < 1024; i += 256) {
    int kk = i >> 5, ll = i & 31;
    sgt[i] = gp_sign_rt(kk ^ ll, ll);
  }
  const float4* xr = (const float4*)(x + (size_t)m * K_FULL);
  float4* xs4 = (float4*)xs;
  for (int i = t; i < 2048; i += 256) xs4[i] = xr[i];
  __syncthreads();
  int k = t & 31, ol = t >> 5;
  int o = o0 + ol;
  const float* wrow = w + (size_t)o * K_FULL;
  float acc = 0.f;
  for (int l = 0; l < 32; ++l) {
    float s = sgt[(k << 5) + l];
    const float* wp = wrow + (k ^ l);
    const float* xp = xs + l;
    float part = 0.f;
#pragma unroll 8
    for (int i = 0; i < 256; ++i) part += xp[i << 5] * wp[i << 5];
    acc += part * s;
  }
  float ss = acc * acc;
  for (int msk = 1; msk < 32; msk <<= 1) ss += __shfl_xor(ss, msk, 32);
  out[((size_t)m * 256 + o) * 32 + k] = acc * rsqrtf(ss + 1e-6f);
}

extern "C" void kernel_launch(void* const* d_in, const int* in_sizes, int n_in,
                              void* d_out, int out_size, void* d_ws, size_t ws_size,
                              hipStream_t stream) {
  const float* x = (const float*)d_in[0];
  const float* w = (const float*)d_in[1];
  float* out = (float*)d_out;

  size_t agE = (size_t)M2 * K2;        // 16.8M f16 = 33.5 MB
  size_t btE = (size_t)N2 * K2;        // 4.2M  f16 =  8.4 MB
  size_t pE  = (size_t)M2 * N2;        // 16.8M f32 = 67 MB
  size_t need = (agE + btE) * sizeof(f16) + pE * sizeof(float);  // ~109 MB

  if (ws_size >= need) {
    f16* Ag = (f16*)d_ws;
    f16* Bt = Ag + agE;
    float* P = (float*)(Bt + btE);
    fwd_x_kernel<<<dim3(M_DIM), dim3(256), 0, stream>>>(x, Ag);
    fwd_w_kernel<<<dim3(256), dim3(256), 0, stream>>>(w, Bt);
    gemm_mat_kernel<<<dim3(N2 / BN, M2 / BM), dim3(256), 0, stream>>>(Ag, Bt, P);
    inv_norm_kernel<<<dim3(M_DIM), dim3(256), 0, stream>>>(P, out);
  } else {
    naive_vl_kernel<<<dim3(M_DIM, 32), dim3(256), 0, stream>>>(x, w, out);
  }
}

// Round 5
// 232.217 us; speedup vs baseline: 2.3560x; 1.1400x over previous
//
#include <hip/hip_runtime.h>
#include <hip/hip_bf16.h>
#include <stdint.h>

typedef _Float16 f16;
typedef __attribute__((ext_vector_type(8))) _Float16 f16x8;
typedef __attribute__((ext_vector_type(4))) float f32x4;

#define M_DIM 2048    // B*S multivector rows
#define K_FULL 8192   // IN*32 (fallback path)
#define M2 8192       // M_DIM*4   (GEMM rows: (m,c))
#define K2 2048       // IN*8      (GEMM K: (i,t,p))
#define N2 2048       // OUT*8     (GEMM cols: (o,r,q))
#define BM 128
#define BN 128
#define BK 32
#define PSTR 132      // epilogue LDS stride (floats), multiple of 4 for b128

// ================= compile-time Cl(4,1) -> M(4,C) tables =================
struct CMat { int re[4][4]; int im[4][4]; };

constexpr CMat cmul(const CMat& A, const CMat& B) {
  CMat C{};
  for (int r = 0; r < 4; ++r)
    for (int c = 0; c < 4; ++c) {
      int re = 0, im = 0;
      for (int t = 0; t < 4; ++t) {
        re += A.re[r][t] * B.re[t][c] - A.im[r][t] * B.im[t][c];
        im += A.re[r][t] * B.im[t][c] + A.im[r][t] * B.re[t][c];
      }
      C.re[r][c] = re; C.im[r][c] = im;
    }
  return C;
}

constexpr int gp_sign_ct(int a, int b) {
  int sw = 0;
  for (int t = a >> 1; t; t >>= 1) {
    int x = t & b;
    while (x) { sw += x & 1; x >>= 1; }
  }
  int s = (sw & 1) ? -1 : 1;
  if ((a & b) & 16) s = -s;   // e5^2 = -1
  return s;
}

struct Tables {
  int8_t f_idx[32][4]; int8_t f_sgn[32][4];  // slot -> 4 (blade, sign)
  int8_t g_idx[32][4]; int8_t g_sgn[32][4];  // blade -> 4 (slot, sign)
  bool ok;
};

constexpr Tables make_tables() {
  // gamma matrices: g1..g4 square to +I, g5 to -I, all anticommute
  CMat G[5] = {
    { {{0,0,0,1},{0,0,1,0},{0,1,0,0},{1,0,0,0}},       // s1 x s1
      {{0,0,0,0},{0,0,0,0},{0,0,0,0},{0,0,0,0}} },
    { {{0,0,0,0},{0,0,0,0},{0,0,0,0},{0,0,0,0}},       // s1 x s2
      {{0,0,0,-1},{0,0,1,0},{0,-1,0,0},{1,0,0,0}} },
    { {{0,0,1,0},{0,0,0,-1},{1,0,0,0},{0,-1,0,0}},     // s1 x s3
      {{0,0,0,0},{0,0,0,0},{0,0,0,0},{0,0,0,0}} },
    { {{0,0,0,0},{0,0,0,0},{0,0,0,0},{0,0,0,0}},       // s2 x I
      {{0,0,-1,0},{0,0,0,-1},{1,0,0,0},{0,1,0,0}} },
    { {{0,0,0,0},{0,0,0,0},{0,0,0,0},{0,0,0,0}},       // i * s3 x I
      {{1,0,0,0},{0,1,0,0},{0,0,-1,0},{0,0,0,-1}} } };
  CMat ID{ {{1,0,0,0},{0,1,0,0},{0,0,1,0},{0,0,0,1}},
           {{0,0,0,0},{0,0,0,0},{0,0,0,0},{0,0,0,0}} };
  CMat U[32] = {};
  for (int A = 0; A < 32; ++A) {
    CMat u = ID;
    for (int b = 0; b < 5; ++b) if (A & (1 << b)) u = cmul(u, G[b]);
    U[A] = u;
  }
  bool ok = true;
  // full homomorphism check vs the reference Cayley table convention
  for (int a = 0; a < 32; ++a)
    for (int b = 0; b < 32; ++b) {
      CMat P = cmul(U[a], U[b]);
      int s = gp_sign_ct(a, b);
      const CMat& T = U[a ^ b];
      for (int r = 0; r < 4; ++r)
        for (int c = 0; c < 4; ++c)
          if (P.re[r][c] != s * T.re[r][c] || P.im[r][c] != s * T.im[r][c]) ok = false;
    }
  Tables t{};
  int cnt[32] = {};
  for (int A = 0; A < 32; ++A) {
    int n = 0;
    for (int r = 0; r < 4; ++r)
      for (int c = 0; c < 4; ++c) {
        int vr = U[A].re[r][c], vi = U[A].im[r][c];
        if (vr) {
          int s = (r * 4 + c) * 2;
          if (n < 4 && cnt[s] < 4) {
            t.g_idx[A][n] = (int8_t)s; t.g_sgn[A][n] = (int8_t)vr;
            t.f_idx[s][cnt[s]] = (int8_t)A; t.f_sgn[s][cnt[s]] = (int8_t)vr;
            cnt[s]++;
          } else ok = false;
          n++;
        }
        if (vi) {
          int s = (r * 4 + c) * 2 + 1;
          if (n < 4 && cnt[s] < 4) {
            t.g_idx[A][n] = (int8_t)s; t.g_sgn[A][n] = (int8_t)vi;
            t.f_idx[s][cnt[s]] = (int8_t)A; t.f_sgn[s][cnt[s]] = (int8_t)vi;
            cnt[s]++;
          } else ok = false;
          n++;
        }
      }
    if (n != 4) ok = false;
  }
  for (int s = 0; s < 32; ++s) if (cnt[s] != 4) ok = false;
  t.ok = ok;
  return t;
}

constexpr Tables HT = make_tables();
static_assert(HT.ok, "Cl(4,1) -> M(4,C) homomorphism check FAILED");

// slot numbering: s = (r*4+c)*2 + p, matrix entry (row r, col c), p: 0=re 1=im

__device__ __forceinline__ void async16(const f16* g, f16* l) {
  __builtin_amdgcn_global_load_lds(
      (const __attribute__((address_space(1))) uint32_t*)g,
      (__attribute__((address_space(3))) uint32_t*)l,
      16, 0, 0);
}

__device__ __forceinline__ float gp_sign_rt(int a, int b) {
  int sw = 0;
  for (int t = a >> 1; t; t >>= 1) sw += __popc(t & b);
  float s = (sw & 1) ? -1.0f : 1.0f;
  if ((a & b) & 16) s = -s;
  return s;
}

// ---- forward transform of x: Ag[(m*4+c)*K2 + i*8 + t*2 + p] = part_p X_{m,i}[t][c]
__global__ __launch_bounds__(256) void fwd_x_kernel(const float* __restrict__ x,
                                                    f16* __restrict__ Ag) {
  int tid = blockIdx.x * 256 + threadIdx.x;   // (m,i)
  int m = tid >> 8, i = tid & 255;
  const float4* xp = (const float4*)(x + (size_t)tid * 32);
  float xv[32];
#pragma unroll
  for (int q = 0; q < 8; ++q) {
    float4 v = xp[q];
    xv[q * 4] = v.x; xv[q * 4 + 1] = v.y; xv[q * 4 + 2] = v.z; xv[q * 4 + 3] = v.w;
  }
  float sv[32];
#pragma unroll
  for (int s = 0; s < 32; ++s)
    sv[s] = (float)HT.f_sgn[s][0] * xv[HT.f_idx[s][0]]
          + (float)HT.f_sgn[s][1] * xv[HT.f_idx[s][1]]
          + (float)HT.f_sgn[s][2] * xv[HT.f_idx[s][2]]
          + (float)HT.f_sgn[s][3] * xv[HT.f_idx[s][3]];
#pragma unroll
  for (int c = 0; c < 4; ++c) {
    f16x8 h;
#pragma unroll
    for (int e = 0; e < 8; ++e) {   // e = t*2+p -> slot (t*4+c)*2+p = t*8+c*2+p
      int t = e >> 1, p = e & 1;
      h[e] = (f16)sv[t * 8 + c * 2 + p];
    }
    *(f16x8*)(Ag + ((size_t)(m * 4 + c)) * K2 + i * 8) = h;
  }
}

// ---- forward transform of w: Bt[(o*8+r*2+q)*K2 + i*8 + t*2 + p]
//      q=0: (p==0? ReW[r][t] : -ImW[r][t]);  q=1: (p==0? ImW[r][t] : ReW[r][t])
__global__ __launch_bounds__(256) void fwd_w_kernel(const float* __restrict__ w,
                                                    f16* __restrict__ Bt) {
  int tid = blockIdx.x * 256 + threadIdx.x;   // (o,i)
  int o = tid >> 8, i = tid & 255;
  const float4* wp = (const float4*)(w + (size_t)tid * 32);
  float wv[32];
#pragma unroll
  for (int q = 0; q < 8; ++q) {
    float4 v = wp[q];
    wv[q * 4] = v.x; wv[q * 4 + 1] = v.y; wv[q * 4 + 2] = v.z; wv[q * 4 + 3] = v.w;
  }
  float sv[32];
#pragma unroll
  for (int s = 0; s < 32; ++s)
    sv[s] = (float)HT.f_sgn[s][0] * wv[HT.f_idx[s][0]]
          + (float)HT.f_sgn[s][1] * wv[HT.f_idx[s][1]]
          + (float)HT.f_sgn[s][2] * wv[HT.f_idx[s][2]]
          + (float)HT.f_sgn[s][3] * wv[HT.f_idx[s][3]];
#pragma unroll
  for (int r = 0; r < 4; ++r)
#pragma unroll
    for (int q = 0; q < 2; ++q) {
      f16x8 h;
#pragma unroll
      for (int e = 0; e < 8; ++e) {
        int t = e >> 1, p = e & 1;
        float re = sv[(r * 4 + t) * 2], im = sv[(r * 4 + t) * 2 + 1];
        float v = (q == 0) ? (p == 0 ? re : -im) : (p == 0 ? im : re);
        h[e] = (f16)v;
      }
      *(f16x8*)(Bt + ((size_t)(o * 8 + r * 2 + q)) * K2 + i * 8) = h;
    }
}

// ---- fused GEMM + inverse transform + normalize ----
// P tile (128x128) stays in LDS; out written directly.
// Norm identity: sum_k v_k^2 = 0.25 * sum_s y_s^2  (Phi^T Phi = Phi Phi^T = 4I).
__global__ __launch_bounds__(256) void gemm_fused_kernel(const f16* __restrict__ A,
                                                         const f16* __restrict__ Bw,
                                                         float* __restrict__ out) {
  __shared__ __align__(16) char smem[BM * PSTR * 4];   // 67584 B
  f16* As = (f16*)smem;                                // 8 KB (staging phase)
  f16* Bs = (f16*)(smem + BM * BK * 2);                // 8 KB
  float* ps = (float*)smem;                            // epilogue phase
  const int t = threadIdx.x;
  const int wave = t >> 6, lane = t & 63;
  const int wr = wave >> 1, wc = wave & 1;
  const int g = lane >> 4, lc = lane & 15;
  const int m0 = blockIdx.y * BM, n0 = blockIdx.x * BN;

  f32x4 acc[4][4];
#pragma unroll
  for (int i = 0; i < 4; ++i)
#pragma unroll
    for (int j = 0; j < 4; ++j) {
      acc[i][j][0] = 0.f; acc[i][j][1] = 0.f; acc[i][j][2] = 0.f; acc[i][j][3] = 0.f;
    }

  const f16* agp[2]; const f16* bgp[2];
  f16* alp[2]; f16* blp[2];
#pragma unroll
  for (int q = 0; q < 2; ++q) {
    int chunk = (q << 8) + (wave << 6) + lane;
    int row = chunk >> 2;
    int gk = ((chunk & 3) ^ ((row >> 1) & 3)) << 3;  // XOR-swizzled source chunk
    agp[q] = A  + (size_t)(m0 + row) * K2 + gk;
    bgp[q] = Bw + (size_t)(n0 + row) * K2 + gk;
    alp[q] = As + (q << 11) + (wave << 9);
    blp[q] = Bs + (q << 11) + (wave << 9);
  }

  const int swz = (lc >> 1) & 3;
  int aoff[4], boff[4];
#pragma unroll
  for (int i = 0; i < 4; ++i) {
    aoff[i] = ((wr << 6) + (i << 4) + lc) * BK + ((g ^ swz) << 3);
    boff[i] = ((wc << 6) + (i << 4) + lc) * BK + ((g ^ swz) << 3);
  }

  for (int kk = 0; kk < K2; kk += BK) {
    async16(agp[0] + kk, alp[0]);
    async16(agp[1] + kk, alp[1]);
    async16(bgp[0] + kk, blp[0]);
    async16(bgp[1] + kk, blp[1]);
    __syncthreads();

    f16x8 av[4], bv[4];
#pragma unroll
    for (int i = 0; i < 4; ++i) av[i] = *(const f16x8*)(As + aoff[i]);
#pragma unroll
    for (int i = 0; i < 4; ++i) bv[i] = *(const f16x8*)(Bs + boff[i]);
#pragma unroll
    for (int tm = 0; tm < 4; ++tm)
#pragma unroll
      for (int tn = 0; tn < 4; ++tn)
        acc[tm][tn] = __builtin_amdgcn_mfma_f32_16x16x32_f16(av[tm], bv[tn],
                                                             acc[tm][tn], 0, 0, 0);
    __syncthreads();   // also protects smem reuse below on the last iter
  }

  // ---- epilogue phase 1: accumulators -> LDS tile (row-major, stride PSTR)
#pragma unroll
  for (int tm = 0; tm < 4; ++tm) {
    int rowb = (wr << 6) + (tm << 4) + (g << 2);
#pragma unroll
    for (int tn = 0; tn < 4; ++tn) {
      int col = (wc << 6) + (tn << 4) + lc;
#pragma unroll
      for (int r = 0; r < 4; ++r)
        ps[(rowb + r) * PSTR + col] = acc[tm][tn][r];
    }
  }
  __syncthreads();

  // ---- epilogue phase 2: per (m,o) inverse transform + normalize + store
#pragma unroll
  for (int pi = 0; pi < 2; ++pi) {
    int p = (pi << 8) + t;            // 0..511
    int mh = p >> 4, oh = p & 15;     // local m-group, o-group
    float yv[4][8];
#pragma unroll
    for (int c = 0; c < 4; ++c) {
      const float* row = ps + (mh * 4 + c) * PSTR + oh * 8;
      *(float4*)&yv[c][0] = *(const float4*)row;
      *(float4*)&yv[c][4] = *(const float4*)(row + 4);
    }
    float ss = 0.f;
#pragma unroll
    for (int c = 0; c < 4; ++c)
#pragma unroll
      for (int j = 0; j < 8; ++j) ss += yv[c][j] * yv[c][j];
    float inv = rsqrtf(0.25f * ss + 1e-6f);

    float ov[32];
#pragma unroll
    for (int k = 0; k < 32; ++k) {
      float v = 0.f;
#pragma unroll
      for (int j = 0; j < 4; ++j) {
        constexpr const int8_t (*GI)[4] = HT.g_idx;
        int s = HT.g_idx[k][j];       // compile-time constant after unroll
        int cell = s >> 1;
        int rr = cell >> 2, cc = cell & 3, pp = s & 1;
        float sgn = (float)HT.g_sgn[k][j];
        v += sgn * yv[cc][rr * 2 + pp];
        (void)GI;
      }
      ov[k] = v * 0.25f * inv;
    }
    int m = (m0 >> 2) + mh;           // global multivector row
    int o = (n0 >> 3) + oh;           // global output channel
    float* op = out + (size_t)m * 8192 + o * 32;
#pragma unroll
    for (int q = 0; q < 8; ++q)
      *(float4*)(op + q * 4) = make_float4(ov[q * 4], ov[q * 4 + 1],
                                           ov[q * 4 + 2], ov[q * 4 + 3]);
  }
}

// ---- safety-net fallback (ws too small): straight fp32 ----
__global__ __launch_bounds__(256) void naive_vl_kernel(const float* __restrict__ x,
                                                       const float* __restrict__ w,
                                                       float* __restrict__ out) {
  __shared__ float xs[8192];
  __shared__ float sgt[1024];
  int m = blockIdx.x, o0 = blockIdx.y << 3;
  int t = threadIdx.x;
  for (int i = t; i < 1024; i += 256) {
    int kk = i >> 5, ll = i & 31;
    sgt[i] = gp_sign_rt(kk ^ ll, ll);
  }
  const float4* xr = (const float4*)(x + (size_t)m * K_FULL);
  float4* xs4 = (float4*)xs;
  for (int i = t; i < 2048; i += 256) xs4[i] = xr[i];
  __syncthreads();
  int k = t & 31, ol = t >> 5;
  int o = o0 + ol;
  const float* wrow = w + (size_t)o * K_FULL;
  float acc = 0.f;
  for (int l = 0; l < 32; ++l) {
    float s = sgt[(k << 5) + l];
    const float* wp = wrow + (k ^ l);
    const float* xp = xs + l;
    float part = 0.f;
#pragma unroll 8
    for (int i = 0; i < 256; ++i) part += xp[i << 5] * wp[i << 5];
    acc += part * s;
  }
  float ss = acc * acc;
  for (int msk = 1; msk < 32; msk <<= 1) ss += __shfl_xor(ss, msk, 32);
  out[((size_t)m * 256 + o) * 32 + k] = acc * rsqrtf(ss + 1e-6f);
}

extern "C" void kernel_launch(void* const* d_in, const int* in_sizes, int n_in,
                              void* d_out, int out_size, void* d_ws, size_t ws_size,
                              hipStream_t stream) {
  const float* x = (const float*)d_in[0];
  const float* w = (const float*)d_in[1];
  float* out = (float*)d_out;

  size_t agE = (size_t)M2 * K2;        // 16.8M f16 = 33.5 MB
  size_t btE = (size_t)N2 * K2;        // 4.2M  f16 =  8.4 MB
  size_t need = (agE + btE) * sizeof(f16);  // ~42 MB

  if (ws_size >= need) {
    f16* Ag = (f16*)d_ws;
    f16* Bt = Ag + agE;
    fwd_x_kernel<<<dim3(M_DIM), dim3(256), 0, stream>>>(x, Ag);
    fwd_w_kernel<<<dim3(256), dim3(256), 0, stream>>>(w, Bt);
    gemm_fused_kernel<<<dim3(N2 / BN, M2 / BM), dim3(256), 0, stream>>>(Ag, Bt, out);
  } else {
    naive_vl_kernel<<<dim3(M_DIM, 32), dim3(256), 0, stream>>>(x, w, out);
  }
}

// Round 6
// 232.050 us; speedup vs baseline: 2.3577x; 1.0007x over previous
//
#include <hip/hip_runtime.h>
#include <hip/hip_bf16.h>
#include <stdint.h>

typedef _Float16 f16;
typedef __attribute__((ext_vector_type(8))) _Float16 f16x8;
typedef __attribute__((ext_vector_type(4))) float f32x4;

#define M_DIM 2048    // B*S multivector rows
#define K_FULL 8192   // IN*32 (fallback path)
#define M2 8192       // M_DIM*4   (GEMM rows: (m,c))
#define K2 2048       // IN*8      (GEMM K: (i,t,p))
#define N2 2048       // OUT*8     (GEMM cols: (o,r,q))
#define BM 128
#define BN 128
#define BK 32
#define PSTR 132      // epilogue LDS stride (floats); 132 mod 32 = 4 -> 2-way writes

// ================= compile-time Cl(4,1) -> M(4,C) tables =================
struct CMat { int re[4][4]; int im[4][4]; };

constexpr CMat cmul(const CMat& A, const CMat& B) {
  CMat C{};
  for (int r = 0; r < 4; ++r)
    for (int c = 0; c < 4; ++c) {
      int re = 0, im = 0;
      for (int t = 0; t < 4; ++t) {
        re += A.re[r][t] * B.re[t][c] - A.im[r][t] * B.im[t][c];
        im += A.re[r][t] * B.im[t][c] + A.im[r][t] * B.re[t][c];
      }
      C.re[r][c] = re; C.im[r][c] = im;
    }
  return C;
}

constexpr int gp_sign_ct(int a, int b) {
  int sw = 0;
  for (int t = a >> 1; t; t >>= 1) {
    int x = t & b;
    while (x) { sw += x & 1; x >>= 1; }
  }
  int s = (sw & 1) ? -1 : 1;
  if ((a & b) & 16) s = -s;   // e5^2 = -1
  return s;
}

struct Tables {
  int8_t f_idx[32][4]; int8_t f_sgn[32][4];  // slot -> 4 (blade, sign)
  int8_t g_idx[32][4]; int8_t g_sgn[32][4];  // blade -> 4 (slot, sign)
  bool ok;
};

constexpr Tables make_tables() {
  // gamma matrices: g1..g4 square to +I, g5 to -I, all anticommute
  CMat G[5] = {
    { {{0,0,0,1},{0,0,1,0},{0,1,0,0},{1,0,0,0}},       // s1 x s1
      {{0,0,0,0},{0,0,0,0},{0,0,0,0},{0,0,0,0}} },
    { {{0,0,0,0},{0,0,0,0},{0,0,0,0},{0,0,0,0}},       // s1 x s2
      {{0,0,0,-1},{0,0,1,0},{0,-1,0,0},{1,0,0,0}} },
    { {{0,0,1,0},{0,0,0,-1},{1,0,0,0},{0,-1,0,0}},     // s1 x s3
      {{0,0,0,0},{0,0,0,0},{0,0,0,0},{0,0,0,0}} },
    { {{0,0,0,0},{0,0,0,0},{0,0,0,0},{0,0,0,0}},       // s2 x I
      {{0,0,-1,0},{0,0,0,-1},{1,0,0,0},{0,1,0,0}} },
    { {{0,0,0,0},{0,0,0,0},{0,0,0,0},{0,0,0,0}},       // i * s3 x I
      {{1,0,0,0},{0,1,0,0},{0,0,-1,0},{0,0,0,-1}} } };
  CMat ID{ {{1,0,0,0},{0,1,0,0},{0,0,1,0},{0,0,0,1}},
           {{0,0,0,0},{0,0,0,0},{0,0,0,0},{0,0,0,0}} };
  CMat U[32] = {};
  for (int A = 0; A < 32; ++A) {
    CMat u = ID;
    for (int b = 0; b < 5; ++b) if (A & (1 << b)) u = cmul(u, G[b]);
    U[A] = u;
  }
  bool ok = true;
  // full homomorphism check vs the reference Cayley table convention
  for (int a = 0; a < 32; ++a)
    for (int b = 0; b < 32; ++b) {
      CMat P = cmul(U[a], U[b]);
      int s = gp_sign_ct(a, b);
      const CMat& T = U[a ^ b];
      for (int r = 0; r < 4; ++r)
        for (int c = 0; c < 4; ++c)
          if (P.re[r][c] != s * T.re[r][c] || P.im[r][c] != s * T.im[r][c]) ok = false;
    }
  Tables t{};
  int cnt[32] = {};
  for (int A = 0; A < 32; ++A) {
    int n = 0;
    for (int r = 0; r < 4; ++r)
      for (int c = 0; c < 4; ++c) {
        int vr = U[A].re[r][c], vi = U[A].im[r][c];
        if (vr) {
          int s = (r * 4 + c) * 2;
          if (n < 4 && cnt[s] < 4) {
            t.g_idx[A][n] = (int8_t)s; t.g_sgn[A][n] = (int8_t)vr;
            t.f_idx[s][cnt[s]] = (int8_t)A; t.f_sgn[s][cnt[s]] = (int8_t)vr;
            cnt[s]++;
          } else ok = false;
          n++;
        }
        if (vi) {
          int s = (r * 4 + c) * 2 + 1;
          if (n < 4 && cnt[s] < 4) {
            t.g_idx[A][n] = (int8_t)s; t.g_sgn[A][n] = (int8_t)vi;
            t.f_idx[s][cnt[s]] = (int8_t)A; t.f_sgn[s][cnt[s]] = (int8_t)vi;
            cnt[s]++;
          } else ok = false;
          n++;
        }
      }
    if (n != 4) ok = false;
  }
  for (int s = 0; s < 32; ++s) if (cnt[s] != 4) ok = false;
  t.ok = ok;
  return t;
}

constexpr Tables HT = make_tables();
static_assert(HT.ok, "Cl(4,1) -> M(4,C) homomorphism check FAILED");

// slot numbering: s = (r*4+c)*2 + p, matrix entry (row r, col c), p: 0=re 1=im

__device__ __forceinline__ void async16(const f16* g, f16* l) {
  __builtin_amdgcn_global_load_lds(
      (const __attribute__((address_space(1))) uint32_t*)g,
      (__attribute__((address_space(3))) uint32_t*)l,
      16, 0, 0);
}

__device__ __forceinline__ float gp_sign_rt(int a, int b) {
  int sw = 0;
  for (int t = a >> 1; t; t >>= 1) sw += __popc(t & b);
  float s = (sw & 1) ? -1.0f : 1.0f;
  if ((a & b) & 16) s = -s;
  return s;
}

// ---- forward transform of x: Ag[(m*4+c)*K2 + i*8 + t*2 + p] = part_p X_{m,i}[t][c]
// One block per m; x row staged through LDS (pad 33) so global reads coalesce.
__global__ __launch_bounds__(256) void fwd_x_kernel(const float* __restrict__ x,
                                                    f16* __restrict__ Ag) {
  __shared__ float xs[256 * 33];   // 33792 B
  const int m = blockIdx.x, t = threadIdx.x;
  const float4* src = (const float4*)(x + (size_t)m * 8192);
#pragma unroll
  for (int c = t; c < 2048; c += 256) {      // fully coalesced 16B loads
    float4 v = src[c];
    float* d = xs + (c >> 3) * 33 + ((c & 7) << 2);
    d[0] = v.x; d[1] = v.y; d[2] = v.z; d[3] = v.w;
  }
  __syncthreads();
  const float* xv = xs + t * 33;             // bank = (t+e)%32: conflict-free
  float sv[32];
#pragma unroll
  for (int s = 0; s < 32; ++s)
    sv[s] = (float)HT.f_sgn[s][0] * xv[HT.f_idx[s][0]]
          + (float)HT.f_sgn[s][1] * xv[HT.f_idx[s][1]]
          + (float)HT.f_sgn[s][2] * xv[HT.f_idx[s][2]]
          + (float)HT.f_sgn[s][3] * xv[HT.f_idx[s][3]];
#pragma unroll
  for (int c = 0; c < 4; ++c) {
    f16x8 h;
#pragma unroll
    for (int e = 0; e < 8; ++e) {   // e = t*2+p -> slot (tt*4+c)*2+p = tt*8+c*2+p
      int tt = e >> 1, p = e & 1;
      h[e] = (f16)sv[tt * 8 + c * 2 + p];
    }
    *(f16x8*)(Ag + ((size_t)(m * 4 + c)) * K2 + t * 8) = h;
  }
}

// ---- forward transform of w: Bt[(o*8+r*2+q)*K2 + i*8 + t*2 + p]
//      q=0: (p==0? ReW[r][t] : -ImW[r][t]);  q=1: (p==0? ImW[r][t] : ReW[r][t])
__global__ __launch_bounds__(256) void fwd_w_kernel(const float* __restrict__ w,
                                                    f16* __restrict__ Bt) {
  __shared__ float xs[256 * 33];
  const int o = blockIdx.x, t = threadIdx.x;
  const float4* src = (const float4*)(w + (size_t)o * 8192);
#pragma unroll
  for (int c = t; c < 2048; c += 256) {
    float4 v = src[c];
    float* d = xs + (c >> 3) * 33 + ((c & 7) << 2);
    d[0] = v.x; d[1] = v.y; d[2] = v.z; d[3] = v.w;
  }
  __syncthreads();
  const float* wv = xs + t * 33;
  float sv[32];
#pragma unroll
  for (int s = 0; s < 32; ++s)
    sv[s] = (float)HT.f_sgn[s][0] * wv[HT.f_idx[s][0]]
          + (float)HT.f_sgn[s][1] * wv[HT.f_idx[s][1]]
          + (float)HT.f_sgn[s][2] * wv[HT.f_idx[s][2]]
          + (float)HT.f_sgn[s][3] * wv[HT.f_idx[s][3]];
#pragma unroll
  for (int r = 0; r < 4; ++r)
#pragma unroll
    for (int q = 0; q < 2; ++q) {
      f16x8 h;
#pragma unroll
      for (int e = 0; e < 8; ++e) {
        int tt = e >> 1, p = e & 1;
        float re = sv[(r * 4 + tt) * 2], im = sv[(r * 4 + tt) * 2 + 1];
        float v = (q == 0) ? (p == 0 ? re : -im) : (p == 0 ? im : re);
        h[e] = (f16)v;
      }
      *(f16x8*)(Bt + ((size_t)(o * 8 + r * 2 + q)) * K2 + t * 8) = h;
    }
}

// ---- fused GEMM + inverse transform + normalize ----
// Epilogue runs in TWO 64-row halves so LDS stays at 33.8 KB (4 blocks/CU).
// Norm identity: sum_k v_k^2 = 0.25 * sum_s y_s^2  (Phi Phi^T = 4I).
__global__ __launch_bounds__(256) void gemm_fused_kernel(const f16* __restrict__ A,
                                                         const f16* __restrict__ Bw,
                                                         float* __restrict__ out) {
  __shared__ __align__(16) char smem[64 * PSTR * 4];   // 33792 B
  f16* As = (f16*)smem;                                // 8 KB (staging phase)
  f16* Bs = (f16*)(smem + BM * BK * 2);                // 8 KB
  float* ps = (float*)smem;                            // epilogue phase (aliased)
  const int t = threadIdx.x;
  const int wave = t >> 6, lane = t & 63;
  const int wr = wave >> 1, wc = wave & 1;
  const int g = lane >> 4, lc = lane & 15;
  const int m0 = blockIdx.y * BM, n0 = blockIdx.x * BN;

  f32x4 acc[4][4];
#pragma unroll
  for (int i = 0; i < 4; ++i)
#pragma unroll
    for (int j = 0; j < 4; ++j) {
      acc[i][j][0] = 0.f; acc[i][j][1] = 0.f; acc[i][j][2] = 0.f; acc[i][j][3] = 0.f;
    }

  const f16* agp[2]; const f16* bgp[2];
  f16* alp[2]; f16* blp[2];
#pragma unroll
  for (int q = 0; q < 2; ++q) {
    int chunk = (q << 8) + (wave << 6) + lane;
    int row = chunk >> 2;
    int gk = ((chunk & 3) ^ ((row >> 1) & 3)) << 3;  // XOR-swizzled source chunk
    agp[q] = A  + (size_t)(m0 + row) * K2 + gk;
    bgp[q] = Bw + (size_t)(n0 + row) * K2 + gk;
    alp[q] = As + (q << 11) + (wave << 9);
    blp[q] = Bs + (q << 11) + (wave << 9);
  }

  const int swz = (lc >> 1) & 3;
  int aoff[4], boff[4];
#pragma unroll
  for (int i = 0; i < 4; ++i) {
    aoff[i] = ((wr << 6) + (i << 4) + lc) * BK + ((g ^ swz) << 3);
    boff[i] = ((wc << 6) + (i << 4) + lc) * BK + ((g ^ swz) << 3);
  }

  for (int kk = 0; kk < K2; kk += BK) {
    async16(agp[0] + kk, alp[0]);
    async16(agp[1] + kk, alp[1]);
    async16(bgp[0] + kk, blp[0]);
    async16(bgp[1] + kk, blp[1]);
    __syncthreads();

    f16x8 av[4], bv[4];
#pragma unroll
    for (int i = 0; i < 4; ++i) av[i] = *(const f16x8*)(As + aoff[i]);
#pragma unroll
    for (int i = 0; i < 4; ++i) bv[i] = *(const f16x8*)(Bs + boff[i]);
#pragma unroll
    for (int tm = 0; tm < 4; ++tm)
#pragma unroll
      for (int tn = 0; tn < 4; ++tn)
        acc[tm][tn] = __builtin_amdgcn_mfma_f32_16x16x32_f16(av[tm], bv[tn],
                                                             acc[tm][tn], 0, 0, 0);
    __syncthreads();   // also protects smem reuse in the epilogue
  }

  // ---- epilogue: two 64-row halves through 33.8 KB LDS ----
#pragma unroll
  for (int half = 0; half < 2; ++half) {
    if (half) __syncthreads();           // prev phase-2 reads done before rewrite
    if (wr == half) {
#pragma unroll
      for (int tm = 0; tm < 4; ++tm) {
        int rowl = (tm << 4) + (g << 2);
#pragma unroll
        for (int tn = 0; tn < 4; ++tn) {
          int col = (wc << 6) + (tn << 4) + lc;
#pragma unroll
          for (int r = 0; r < 4; ++r)
            ps[(rowl + r) * PSTR + col] = acc[tm][tn][r];
        }
      }
    }
    __syncthreads();

    // 256 threads process the 16 m-groups x 16 o-groups of this half
    const int mh = t >> 4, oh = t & 15;
    float yv[4][8];
#pragma unroll
    for (int c = 0; c < 4; ++c) {
      const float* row = ps + (mh * 4 + c) * PSTR + oh * 8;
      *(float4*)&yv[c][0] = *(const float4*)row;
      *(float4*)&yv[c][4] = *(const float4*)(row + 4);
    }
    float ss = 0.f;
#pragma unroll
    for (int c = 0; c < 4; ++c)
#pragma unroll
      for (int j = 0; j < 8; ++j) ss += yv[c][j] * yv[c][j];
    float inv = rsqrtf(0.25f * ss + 1e-6f);

    float ov[32];
#pragma unroll
    for (int k = 0; k < 32; ++k) {
      float v = 0.f;
#pragma unroll
      for (int j = 0; j < 4; ++j) {
        int s = HT.g_idx[k][j];       // compile-time constant after unroll
        int cell = s >> 1;
        int rr = cell >> 2, cc = cell & 3, pp = s & 1;
        float sgn = (float)HT.g_sgn[k][j];
        v += sgn * yv[cc][rr * 2 + pp];
      }
      ov[k] = v * 0.25f * inv;
    }
    int m = (m0 >> 2) + (half << 4) + mh;   // global multivector row
    int o = (n0 >> 3) + oh;                 // global output channel
    float* op = out + (size_t)m * 8192 + o * 32;
#pragma unroll
    for (int q = 0; q < 8; ++q)
      *(float4*)(op + q * 4) = make_float4(ov[q * 4], ov[q * 4 + 1],
                                           ov[q * 4 + 2], ov[q * 4 + 3]);
  }
}

// ---- safety-net fallback (ws too small): straight fp32 ----
__global__ __launch_bounds__(256) void naive_vl_kernel(const float* __restrict__ x,
                                                       const float* __restrict__ w,
                                                       float* __restrict__ out) {
  __shared__ float xs[8192];
  __shared__ float sgt[1024];
  int m = blockIdx.x, o0 = blockIdx.y << 3;
  int t = threadIdx.x;
  for (int i = t; i < 1024; i += 256) {
    int kk = i >> 5, ll = i & 31;
    sgt[i] = gp_sign_rt(kk ^ ll, ll);
  }
  const float4* xr = (const float4*)(x + (size_t)m * K_FULL);
  float4* xs4 = (float4*)xs;
  for (int i = t; i < 2048; i += 256) xs4[i] = xr[i];
  __syncthreads();
  int k = t & 31, ol = t >> 5;
  int o = o0 + ol;
  const float* wrow = w + (size_t)o * K_FULL;
  float acc = 0.f;
  for (int l = 0; l < 32; ++l) {
    float s = sgt[(k << 5) + l];
    const float* wp = wrow + (k ^ l);
    const float* xp = xs + l;
    float part = 0.f;
#pragma unroll 8
    for (int i = 0; i < 256; ++i) part += xp[i << 5] * wp[i << 5];
    acc += part * s;
  }
  float ss = acc * acc;
  for (int msk = 1; msk < 32; msk <<= 1) ss += __shfl_xor(ss, msk, 32);
  out[((size_t)m * 256 + o) * 32 + k] = acc * rsqrtf(ss + 1e-6f);
}

extern "C" void kernel_launch(void* const* d_in, const int* in_sizes, int n_in,
                              void* d_out, int out_size, void* d_ws, size_t ws_size,
                              hipStream_t stream) {
  const float* x = (const float*)d_in[0];
  const float* w = (const float*)d_in[1];
  float* out = (float*)d_out;

  size_t agE = (size_t)M2 * K2;        // 16.8M f16 = 33.5 MB
  size_t btE = (size_t)N2 * K2;        // 4.2M  f16 =  8.4 MB
  size_t need = (agE + btE) * sizeof(f16);  // ~42 MB

  if (ws_size >= need) {
    f16* Ag = (f16*)d_ws;
    f16* Bt = Ag + agE;
    fwd_x_kernel<<<dim3(M_DIM), dim3(256), 0, stream>>>(x, Ag);
    fwd_w_kernel<<<dim3(256), dim3(256), 0, stream>>>(w, Bt);
    gemm_fused_kernel<<<dim3(N2 / BN, M2 / BM), dim3(256), 0, stream>>>(Ag, Bt, out);
  } else {
    naive_vl_kernel<<<dim3(M_DIM, 32), dim3(256), 0, stream>>>(x, w, out);
  }
}